// Round 6
// baseline (499.980 us; speedup 1.0000x reference)
//
#include <hip/hip_runtime.h>

#define N_NODES 100000
#define N_EDGES 1200000
#define N_GRAPHS 512
#define F 60
#define NPW 4    // nodes per wave-iteration in k_layer
#define CAP 48   // padded CSR bucket capacity (Poisson(12): P(deg>=48) ~ 1e-11/node; held r2-r5)

// ---------------- padded CSR scatter: one atomic per edge ----------------
__global__ void k_scatter_pad(const int* __restrict__ src, const int* __restrict__ dst,
                              const float* __restrict__ ew, int* __restrict__ cursor,
                              int2* __restrict__ csr, int E) {
    int e = blockIdx.x * 256 + threadIdx.x;
    if (e >= E) return;
    int s = src[e], d = dst[e];
    int pos = atomicAdd(&cursor[d], 1);
    if (pos < CAP) {
        unsigned long long pk = (unsigned)s |
            ((unsigned long long)__float_as_uint(ew[e]) << 32);   // .x=src, .y=ew
        __builtin_nontemporal_store(pk, (unsigned long long*)&csr[(size_t)d * CAP + pos]);
    }
}

// ---------------- deg -> dinv: wave per node, shuffle reduce ----------------
__global__ void k_deg(const int2* __restrict__ csr, const int* __restrict__ cnt,
                      float* __restrict__ dinv, int n) {
    int v = blockIdx.x * 4 + (threadIdx.x >> 6);
    int lane = threadIdx.x & 63;
    if (v >= n) return;
    int m = min(cnt[v], CAP);
    float w = (lane < m) ? __int_as_float(csr[(size_t)v * CAP + lane].y) : 0.f;
    #pragma unroll
    for (int off = 32; off > 0; off >>= 1) w += __shfl_xor(w, off);
    if (lane == 0) dinv[v] = rsqrtf(w + 1.0f);   // +1 self-loop
}

// ---------------- fused layer ----------------
// FIRST: Hin = x (stride 10); computes nrm = dinv[s]*ew*dinv[v] on the fly and
//        REWRITES csr[..].y with it (layers 2-4 then read it directly).
// else : Hin stride 64 (padded rows).
// Phase 1: per-wave gather-accumulate acc[t] (feature = lane), 8 gathers in flight.
// Phase 2: acc -> per-wave LDS; broadcast 4 k at a time via uniform ds_read_b128;
//          W column stays in LDS (Ws[k][lane], conflict-free).
template<bool FIRST>
__global__ void __launch_bounds__(256) k_layer(
        const float* __restrict__ Hin, const float* __restrict__ W,
        const float* __restrict__ bias,
        int2* __restrict__ csr, const int* __restrict__ cnt,
        const float* __restrict__ dinv,
        float* __restrict__ Hout, int n) {
    constexpr int WIN = FIRST ? 10 : 60;
    constexpr int KQ  = (WIN + 3) / 4;        // quads (FIRST: 3 -> rows 10,11 zero-padded)
    __shared__ float Ws[KQ * 4 * 64];         // Ws[k*64+j] = W[k][j]; pad k>=WIN or j>=F -> 0
    __shared__ __align__(16) float accS[4][NPW][64];

    for (int i = threadIdx.x; i < KQ * 4 * 64; i += 256) {
        int k = i >> 6, j = i & 63;
        Ws[i] = (j < F && k < WIN) ? W[k * F + j] : 0.f;
    }
    __syncthreads();

    int wave = threadIdx.x >> 6;
    int lane = threadIdx.x & 63;
    int l10 = min(lane & 15, 9);              // FIRST-layer gather column (clamped)
    float bj = (lane < F) ? bias[lane] : 0.f;
    const int NGRP = n / NPW;                 // 25000, exact

    for (int grp = blockIdx.x * 4 + wave; grp < NGRP; grp += gridDim.x * 4) {
        int base = grp * NPW;

        // ---- phase 1: gather-accumulate NPW nodes ----
        float acc[NPW];
        #pragma unroll
        for (int t = 0; t < NPW; ++t) {
            int v = base + t;
            float di = dinv[v];
            float self = FIRST ? Hin[v * 10 + l10] : Hin[(size_t)v * 64 + lane];
            float a = self * (di * di);
            int m = min(cnt[v], CAP);
            int2* seg = csr + (size_t)v * CAP;
            int e = 0;
            if (!FIRST) {
                const int4* seg4 = (const int4*)seg;
                for (; e + 8 <= m; e += 8) {          // 8 gathers in flight
                    int4 q0 = seg4[e / 2], q1 = seg4[e / 2 + 1];
                    int4 q2 = seg4[e / 2 + 2], q3 = seg4[e / 2 + 3];
                    float g0 = Hin[(size_t)q0.x * 64 + lane];
                    float g1 = Hin[(size_t)q0.z * 64 + lane];
                    float g2 = Hin[(size_t)q1.x * 64 + lane];
                    float g3 = Hin[(size_t)q1.z * 64 + lane];
                    float g4 = Hin[(size_t)q2.x * 64 + lane];
                    float g5 = Hin[(size_t)q2.z * 64 + lane];
                    float g6 = Hin[(size_t)q3.x * 64 + lane];
                    float g7 = Hin[(size_t)q3.z * 64 + lane];
                    a = fmaf(__int_as_float(q0.y), g0, a);
                    a = fmaf(__int_as_float(q0.w), g1, a);
                    a = fmaf(__int_as_float(q1.y), g2, a);
                    a = fmaf(__int_as_float(q1.w), g3, a);
                    a = fmaf(__int_as_float(q2.y), g4, a);
                    a = fmaf(__int_as_float(q2.w), g5, a);
                    a = fmaf(__int_as_float(q3.y), g6, a);
                    a = fmaf(__int_as_float(q3.w), g7, a);
                }
                for (; e + 2 <= m; e += 2) {
                    int2 p0 = seg[e], p1 = seg[e + 1];
                    float g0 = Hin[(size_t)p0.x * 64 + lane];
                    float g1 = Hin[(size_t)p1.x * 64 + lane];
                    a = fmaf(__int_as_float(p0.y), g0, a);
                    a = fmaf(__int_as_float(p1.y), g1, a);
                }
                if (e < m) {
                    int2 p = seg[e];
                    a = fmaf(__int_as_float(p.y), Hin[(size_t)p.x * 64 + lane], a);
                }
            } else {
                // layer 1: gather from raw x, compute+write nrm into csr
                for (; e + 4 <= m; e += 4) {
                    int2 p0 = seg[e], p1 = seg[e + 1], p2 = seg[e + 2], p3 = seg[e + 3];
                    float d0 = dinv[p0.x], d1 = dinv[p1.x], d2 = dinv[p2.x], d3 = dinv[p3.x];
                    float x0 = Hin[p0.x * 10 + l10];
                    float x1 = Hin[p1.x * 10 + l10];
                    float x2 = Hin[p2.x * 10 + l10];
                    float x3 = Hin[p3.x * 10 + l10];
                    float q0 = d0 * __int_as_float(p0.y) * di;
                    float q1 = d1 * __int_as_float(p1.y) * di;
                    float q2 = d2 * __int_as_float(p2.y) * di;
                    float q3 = d3 * __int_as_float(p3.y) * di;
                    seg[e].y     = __float_as_int(q0);
                    seg[e + 1].y = __float_as_int(q1);
                    seg[e + 2].y = __float_as_int(q2);
                    seg[e + 3].y = __float_as_int(q3);
                    a = fmaf(q0, x0, a); a = fmaf(q1, x1, a);
                    a = fmaf(q2, x2, a); a = fmaf(q3, x3, a);
                }
                for (; e < m; ++e) {
                    int2 p = seg[e];
                    float q = dinv[p.x] * __int_as_float(p.y) * di;
                    seg[e].y = __float_as_int(q);
                    a = fmaf(q, Hin[p.x * 10 + l10], a);
                }
                // note: acc lanes (lane&15)>=10 hold a duplicate of feature 9;
                // they multiply zero-padded Ws rows 10,11 in phase 2 -> harmless.
            }
            acc[t] = a;
        }

        // ---- phase 2: MM via LDS quad-broadcast ----
        #pragma unroll
        for (int t = 0; t < NPW; ++t) accS[wave][t][lane] = acc[t];
        float o[NPW];
        #pragma unroll
        for (int t = 0; t < NPW; ++t) o[t] = bj;
        const float4* aq = (const float4*)&accS[wave][0][0];   // [NPW][16 quads]
        #pragma unroll
        for (int kq = 0; kq < KQ; ++kq) {
            float w0 = Ws[(4 * kq + 0) * 64 + lane];
            float w1 = Ws[(4 * kq + 1) * 64 + lane];
            float w2 = Ws[(4 * kq + 2) * 64 + lane];
            float w3 = Ws[(4 * kq + 3) * 64 + lane];
            #pragma unroll
            for (int t = 0; t < NPW; ++t) {
                float4 aa = aq[t * 16 + kq];           // uniform addr -> broadcast
                o[t] = fmaf(aa.x, w0, o[t]);
                o[t] = fmaf(aa.y, w1, o[t]);
                o[t] = fmaf(aa.z, w2, o[t]);
                o[t] = fmaf(aa.w, w3, o[t]);
            }
        }
        #pragma unroll
        for (int t = 0; t < NPW; ++t)
            Hout[(size_t)(base + t) * 64 + lane] = fmaxf(o[t], 0.f);  // pad lanes write 0
    }
}

// ---------------- graph segment starts (batch is sorted) ----------------
__global__ void k_gstart(const int* __restrict__ batch, int* __restrict__ start, int n) {
    int i = blockIdx.x * 256 + threadIdx.x;
    if (i >= n) return;
    int b = batch[i];
    int pb = (i == 0) ? -1 : batch[i - 1];
    for (int g = pb + 1; g <= b; ++g) start[g] = i;
    if (i == n - 1) for (int g = b + 1; g <= N_GRAPHS; ++g) start[g] = n;
}

// ---------------- segment max pool: block per graph, 4 waves strided ----------------
__global__ void k_pool2(const float* __restrict__ H, const int* __restrict__ start,
                        float* __restrict__ g) {
    __shared__ float red[4 * F];
    int gi = blockIdx.x;
    int wave = threadIdx.x >> 6;
    int lane = threadIdx.x & 63;
    int s = start[gi], e = start[gi + 1];
    float m = 0.f;                       // relu output >= 0; empty graph -> 0 (matches ref guard)
    for (int i = s + wave; i < e; i += 4)
        m = fmaxf(m, H[(size_t)i * 64 + lane]);
    if (lane < F) red[wave * F + lane] = m;
    __syncthreads();
    if (threadIdx.x < F) {
        float r = fmaxf(fmaxf(red[threadIdx.x], red[F + threadIdx.x]),
                        fmaxf(red[2 * F + threadIdx.x], red[3 * F + threadIdx.x]));
        g[gi * F + threadIdx.x] = r;
    }
}

// ---------------- MLP head: one block per graph ----------------
__global__ void k_mlp(const float* __restrict__ g,
                      const float* __restrict__ L1w, const float* __restrict__ L1b,
                      const float* __restrict__ L2w, const float* __restrict__ L2b,
                      const float* __restrict__ L3w, const float* __restrict__ L3b,
                      float* __restrict__ out) {
    __shared__ float gin[F], h1[F], h2[10];
    int gi = blockIdx.x;
    int t = threadIdx.x;
    if (t < F) gin[t] = g[gi * F + t];
    __syncthreads();
    if (t < F) {
        float a = L1b[t];
        for (int k = 0; k < F; ++k) a += gin[k] * L1w[k * F + t];
        h1[t] = fmaxf(a, 0.f);
    }
    __syncthreads();
    if (t < 10) {
        float a = L2b[t];
        for (int k = 0; k < F; ++k) a += h1[k] * L2w[k * 10 + t];
        h2[t] = fmaxf(a, 0.f);
    }
    __syncthreads();
    if (t < 2) {
        float a = L3b[t];
        for (int k = 0; k < 10; ++k) a += h2[k] * L3w[k * 2 + t];
        out[gi * 2 + t] = a;
    }
}

extern "C" void kernel_launch(void* const* d_in, const int* in_sizes, int n_in,
                              void* d_out, int out_size, void* d_ws, size_t ws_size,
                              hipStream_t stream) {
    const int n = N_NODES, E = N_EDGES;
    const float* x   = (const float*)d_in[0];
    const int* ei    = (const int*)d_in[1];         // [2, E]
    const int* batch = (const int*)d_in[2];
    const float* ew  = (const float*)d_in[3];
    const float* W1 = (const float*)d_in[4],  *b1 = (const float*)d_in[5];
    const float* W2 = (const float*)d_in[6],  *b2 = (const float*)d_in[7];
    const float* W3 = (const float*)d_in[8],  *b3 = (const float*)d_in[9];
    const float* W4 = (const float*)d_in[10], *b4 = (const float*)d_in[11];
    const float* L1w = (const float*)d_in[12], *L1b = (const float*)d_in[13];
    const float* L2w = (const float*)d_in[14], *L2b = (const float*)d_in[15];
    const float* L3w = (const float*)d_in[16], *L3b = (const float*)d_in[17];
    float* out = (float*)d_out;

    const int* src = ei;
    const int* dst = ei + E;

    // ---- workspace carve (256B aligned) ----
    char* ws = (char*)d_ws;
    size_t off = 0;
    auto carve = [&](size_t bytes) {
        void* p = ws + off;
        off += (bytes + 255) & ~size_t(255);
        return p;
    };
    int*   cnt  = (int*)carve(n * 4);               // atomic cursor == count
    float* dinv = (float*)carve(n * 4);
    int*   gst  = (int*)carve((N_GRAPHS + 1) * 4);
    int2*  csr  = (int2*)carve((size_t)n * CAP * 8);  // packed {src, ew -> nrm}
    float* hA   = (float*)carve((size_t)n * 64 * 4);
    float* hB   = (float*)carve((size_t)n * 64 * 4);
    float* g0   = (float*)carve((size_t)N_GRAPHS * F * 4);
    (void)ws_size;

    const int EB = (E + 255) / 256;
    const int NB = (n + 255) / 256;
    const int WB = (n + 3) / 4;                       // wave-per-node blocks
    const int LB = 2048;                              // persistent k_layer grid (8 blocks/CU)

    // ---- CSR build + small prep ----
    hipMemsetAsync(cnt, 0, n * 4, stream);
    k_scatter_pad<<<EB, 256, 0, stream>>>(src, dst, ew, cnt, csr, E);
    k_gstart<<<NB, 256, 0, stream>>>(batch, gst, n);
    k_deg<<<WB, 256, 0, stream>>>(csr, cnt, dinv, n);

    // ---- 4 fused GCN layers (layer 1 also writes nrm into csr) ----
    k_layer<true ><<<LB, 256, 0, stream>>>(x,  W1, b1, csr, cnt, dinv, hA, n);
    k_layer<false><<<LB, 256, 0, stream>>>(hA, W2, b2, csr, cnt, dinv, hB, n);
    k_layer<false><<<LB, 256, 0, stream>>>(hB, W3, b3, csr, cnt, dinv, hA, n);
    k_layer<false><<<LB, 256, 0, stream>>>(hA, W4, b4, csr, cnt, dinv, hB, n);

    // ---- segment max pool + MLP ----
    k_pool2<<<N_GRAPHS, 256, 0, stream>>>(hB, gst, g0);
    k_mlp<<<N_GRAPHS, 64, 0, stream>>>(g0, L1w, L1b, L2w, L2b, L3w, L3b, out);
}